// Round 3
// baseline (1303.059 us; speedup 1.0000x reference)
//
#include <hip/hip_runtime.h>
#include <stdint.h>

typedef unsigned short u16;
typedef unsigned int   u32;

#define EPS 1e-3f
#define NB 32
#define HW 56
#define CI 256
#define CM 128
#define PIX (NB*HW*HW)   // 100352

__device__ __forceinline__ float asf(u32 i){ union{u32 u; float f;} t; t.u=i; return t.f; }
__device__ __forceinline__ float bf2f(u16 u){ return asf(((u32)u)<<16); }
__device__ __forceinline__ u16 f2bf(float f){
  union{float f; u32 u;} t; t.f = f;
  u32 x = t.u;
  return (u16)((x + 0x7fffu + ((x>>16)&1u)) >> 16);   // RNE
}
// dtype-polymorphic scalar load: isbf -> bf16, else fp32
__device__ __forceinline__ float ldf(const void* p, int i, bool isbf){
  return isbf ? bf2f(((const u16*)p)[i]) : ((const float*)p)[i];
}
// g1 is all-ones: fp32 word0 = 0x3F800000, bf16 pair = 0x3F803F80
__device__ __forceinline__ bool probe_bf16(const void* g1){
  return *(const u32*)g1 == 0x3F803F80u;
}

// ---------------- prep: decode weights to f32, fold BN into A*conv+B ----------------
__global__ __launch_bounds__(256) void kprep(
    const void* __restrict__ w1, const void* __restrict__ b1, const void* __restrict__ g1,
    const void* __restrict__ be1, const void* __restrict__ m1, const void* __restrict__ v1,
    const void* __restrict__ w2, const void* __restrict__ b2, const void* __restrict__ g2,
    const void* __restrict__ be2, const void* __restrict__ m2, const void* __restrict__ v2,
    const void* __restrict__ w3, const void* __restrict__ b3,
    float* __restrict__ wf1, float* __restrict__ wf2, float* __restrict__ wf3,
    float* __restrict__ A1, float* __restrict__ B1,
    float* __restrict__ A2, float* __restrict__ B2, float* __restrict__ b3f){
  const bool isbf = probe_bf16(g1);
  int i = blockIdx.x*256 + threadIdx.x;
  if (i < 32768){ wf1[i] = ldf(w1,i,isbf); wf3[i] = ldf(w3,i,isbf); }
  if (i < 4608)  wf2[i] = ldf(w2,i,isbf);
  if (i < 128){
    float s1 = ldf(g1,i,isbf) * rsqrtf(ldf(v1,i,isbf) + EPS);
    A1[i] = s1;
    B1[i] = ldf(b1,i,isbf)*s1 + ldf(be1,i,isbf) - ldf(m1,i,isbf)*s1;
    float s2 = ldf(g2,i,isbf) * rsqrtf(ldf(v2,i,isbf) + EPS);
    A2[i] = s2;
    B2[i] = ldf(b2,i,isbf)*s2 + ldf(be2,i,isbf) - ldf(m2,i,isbf)*s2;
  }
  if (i < 256) b3f[i] = ldf(b3,i,isbf);
}

// ---------------- conv1 1x1 256->128 + BN + ReLU ----------------
// block: 256 thr = 16 pixels x (16 thr, 8 ch each)
__global__ __launch_bounds__(256) void k1(const void* __restrict__ x,
    const void* __restrict__ g1p,
    const float* __restrict__ wf1, const float* __restrict__ A1v,
    const float* __restrict__ B1v, u16* __restrict__ h1){
  __shared__ float xs[16][CI];
  const int tid = threadIdx.x;
  const long p0 = (long)blockIdx.x * 16;
  const bool isbf = probe_bf16(g1p);
  if (isbf){
    const uint4* xg = (const uint4*)((const u16*)x + p0*CI);
    #pragma unroll
    for (int i = tid; i < 512; i += 256){
      uint4 v = xg[i];
      int px = i >> 5, ch = (i & 31)*8;
      float* d = &xs[px][ch];
      d[0]=asf(v.x<<16); d[1]=asf(v.x&0xffff0000u);
      d[2]=asf(v.y<<16); d[3]=asf(v.y&0xffff0000u);
      d[4]=asf(v.z<<16); d[5]=asf(v.z&0xffff0000u);
      d[6]=asf(v.w<<16); d[7]=asf(v.w&0xffff0000u);
    }
  } else {
    const float4* xg = (const float4*)((const float*)x + p0*CI);
    #pragma unroll
    for (int i = tid; i < 1024; i += 256){
      float4 v = xg[i];
      int px = i >> 6, ch = (i & 63)*4;
      float* d = &xs[px][ch];
      d[0]=v.x; d[1]=v.y; d[2]=v.z; d[3]=v.w;
    }
  }
  __syncthreads();
  const int cg = tid & 15, pix = tid >> 4, c0 = cg*8;
  float acc[8] = {0,0,0,0,0,0,0,0};
  const float* wp = wf1 + c0;
  #pragma unroll 4
  for (int k = 0; k < CI; k++){
    float xv = xs[pix][k];
    float4 wa = *(const float4*)(wp + (size_t)k*CM);
    float4 wb = *(const float4*)(wp + (size_t)k*CM + 4);
    acc[0] += xv*wa.x; acc[1] += xv*wa.y; acc[2] += xv*wa.z; acc[3] += xv*wa.w;
    acc[4] += xv*wb.x; acc[5] += xv*wb.y; acc[6] += xv*wb.z; acc[7] += xv*wb.w;
  }
  const long p = p0 + pix;
  u16 ov[8];
  #pragma unroll
  for (int j = 0; j < 8; j++){
    float r = acc[j]*A1v[c0+j] + B1v[c0+j];
    ov[j] = f2bf(fmaxf(r, 0.f));
  }
  uint4 pk;
  pk.x = (u32)ov[0] | ((u32)ov[1]<<16);
  pk.y = (u32)ov[2] | ((u32)ov[3]<<16);
  pk.z = (u32)ov[4] | ((u32)ov[5]<<16);
  pk.w = (u32)ov[6] | ((u32)ov[7]<<16);
  *(uint4*)(h1 + p*CM + c0) = pk;
}

// ---------------- grouped 3x3 conv (32 groups of 4) + BN + ReLU ----------------
// block = 256 thr, one output row (56 px); lane=pixel, wave handles 8 groups.
#define TW 58       // 56 + 2 zero guard columns
#define CPAD 132    // padded channel stride (u16)
__global__ __launch_bounds__(256) void k2(const u16* __restrict__ h1,
    const float* __restrict__ wf2, const float* __restrict__ A2v,
    const float* __restrict__ B2v, u16* __restrict__ h2){
  __shared__ u16 tile[3][TW][CPAD];   // 45936 B
  __shared__ float wsh[9*4*CM];       // 18432 B
  const int tid = threadIdx.x;
  const int img = blockIdx.x / HW, y = blockIdx.x % HW;
  for (int i = tid; i < 4608; i += 256) wsh[i] = wf2[i];
  #pragma unroll
  for (int r = 0; r < 3; r++){
    const int yy = y + r - 1;
    if (yy < 0 || yy >= HW){
      u32* t = (u32*)&tile[r][0][0];
      for (int i = tid; i < TW*CPAD/2; i += 256) t[i] = 0u;
    } else {
      if (tid < CPAD){ tile[r][0][tid] = 0; tile[r][TW-1][tid] = 0; }
      const uint4* src = (const uint4*)(h1 + (size_t)(img*HW + yy)*HW*CM);
      for (int i = tid; i < 896; i += 256){
        uint4 v = src[i];
        int px = i >> 4, ch = (i & 15)*8;
        u16* d = &tile[r][px+1][ch];
        *(uint2*)d     = make_uint2(v.x, v.y);
        *(uint2*)(d+4) = make_uint2(v.z, v.w);
      }
    }
  }
  __syncthreads();
  const int lane = tid & 63, wv = tid >> 6;
  if (lane >= HW) return;
  const int px = lane;
  float acc[8][4];
  u16 ov[32];
  for (int gi = 0; gi < 8; gi++){
    const int cb = (wv*8 + gi)*4;
    float a0=0.f, a1=0.f, a2=0.f, a3=0.f;
    #pragma unroll
    for (int ky = 0; ky < 3; ky++){
      #pragma unroll
      for (int kx = 0; kx < 3; kx++){
        const u16* hp = &tile[ky][px+kx][cb];
        uint2 hv = *(const uint2*)hp;
        float i0 = asf(hv.x<<16), i1 = asf(hv.x&0xffff0000u);
        float i2 = asf(hv.y<<16), i3 = asf(hv.y&0xffff0000u);
        const float* wp = &wsh[(size_t)((ky*3+kx)*4)*CM + cb];  // wave-uniform -> broadcast
        float4 w0 = *(const float4*)(wp);
        float4 w1 = *(const float4*)(wp+CM);
        float4 w2 = *(const float4*)(wp+2*CM);
        float4 w3 = *(const float4*)(wp+3*CM);
        a0 += i0*w0.x + i1*w1.x + i2*w2.x + i3*w3.x;
        a1 += i0*w0.y + i1*w1.y + i2*w2.y + i3*w3.y;
        a2 += i0*w0.z + i1*w1.z + i2*w2.z + i3*w3.z;
        a3 += i0*w0.w + i1*w1.w + i2*w2.w + i3*w3.w;
      }
    }
    acc[gi][0]=a0; acc[gi][1]=a1; acc[gi][2]=a2; acc[gi][3]=a3;
  }
  const long p = (long)(img*HW + y)*HW + px;
  #pragma unroll
  for (int gi = 0; gi < 8; gi++){
    #pragma unroll
    for (int co = 0; co < 4; co++){
      int c = wv*32 + gi*4 + co;
      float r = acc[gi][co]*A2v[c] + B2v[c];
      ov[gi*4+co] = f2bf(fmaxf(r, 0.f));
    }
  }
  u16* op = h2 + p*CM + wv*32;
  #pragma unroll
  for (int q = 0; q < 4; q++){
    uint4 pk;
    pk.x = (u32)ov[q*8+0] | ((u32)ov[q*8+1]<<16);
    pk.y = (u32)ov[q*8+2] | ((u32)ov[q*8+3]<<16);
    pk.z = (u32)ov[q*8+4] | ((u32)ov[q*8+5]<<16);
    pk.w = (u32)ov[q*8+6] | ((u32)ov[q*8+7]<<16);
    *(uint4*)(op + q*8) = pk;
  }
}

// ---------------- conv3 1x1 128->256 + bias + residual + ReLU ----------------
// block: 256 thr = 16 pixels x (16 thr, 16 ch each)
// Output dtype matches input dtype (probe): fp32 stores or bf16 stores.
__global__ __launch_bounds__(256) void k3(const u16* __restrict__ h2,
    const float* __restrict__ wf3, const float* __restrict__ b3f,
    const void* __restrict__ xin, const void* __restrict__ g1p,
    void* __restrict__ out){
  __shared__ float hs[16][CM];
  const int tid = threadIdx.x;
  const long p0 = (long)blockIdx.x * 16;
  const bool isbf = probe_bf16(g1p);
  const uint4* hg = (const uint4*)(h2 + p0*CM);
  {
    int i = tid;   // exactly 256 uint4 to stage
    uint4 v = hg[i];
    int px = i >> 4, ch = (i & 15)*8;
    float* d = &hs[px][ch];
    d[0]=asf(v.x<<16); d[1]=asf(v.x&0xffff0000u);
    d[2]=asf(v.y<<16); d[3]=asf(v.y&0xffff0000u);
    d[4]=asf(v.z<<16); d[5]=asf(v.z&0xffff0000u);
    d[6]=asf(v.w<<16); d[7]=asf(v.w&0xffff0000u);
  }
  __syncthreads();
  const int cg = tid & 15, pix = tid >> 4, c0 = cg*16;
  float acc[16];
  #pragma unroll
  for (int j = 0; j < 16; j++) acc[j] = 0.f;
  #pragma unroll 2
  for (int k = 0; k < CM; k++){
    float xv = hs[pix][k];
    const float* wp = wf3 + (size_t)k*CI + c0;
    float4 w0 = *(const float4*)(wp);
    float4 w1 = *(const float4*)(wp+4);
    float4 w2 = *(const float4*)(wp+8);
    float4 w3 = *(const float4*)(wp+12);
    acc[0]+=xv*w0.x; acc[1]+=xv*w0.y; acc[2]+=xv*w0.z; acc[3]+=xv*w0.w;
    acc[4]+=xv*w1.x; acc[5]+=xv*w1.y; acc[6]+=xv*w1.z; acc[7]+=xv*w1.w;
    acc[8]+=xv*w2.x; acc[9]+=xv*w2.y; acc[10]+=xv*w2.z; acc[11]+=xv*w2.w;
    acc[12]+=xv*w3.x; acc[13]+=xv*w3.y; acc[14]+=xv*w3.z; acc[15]+=xv*w3.w;
  }
  const long p = p0 + pix;
  float xf[16];
  if (isbf){
    const uint4* xr = (const uint4*)((const u16*)xin + p*CI + c0);
    uint4 xv0 = xr[0], xv1 = xr[1];
    xf[0]=asf(xv0.x<<16); xf[1]=asf(xv0.x&0xffff0000u);
    xf[2]=asf(xv0.y<<16); xf[3]=asf(xv0.y&0xffff0000u);
    xf[4]=asf(xv0.z<<16); xf[5]=asf(xv0.z&0xffff0000u);
    xf[6]=asf(xv0.w<<16); xf[7]=asf(xv0.w&0xffff0000u);
    xf[8]=asf(xv1.x<<16); xf[9]=asf(xv1.x&0xffff0000u);
    xf[10]=asf(xv1.y<<16); xf[11]=asf(xv1.y&0xffff0000u);
    xf[12]=asf(xv1.z<<16); xf[13]=asf(xv1.z&0xffff0000u);
    xf[14]=asf(xv1.w<<16); xf[15]=asf(xv1.w&0xffff0000u);
  } else {
    const float* xr = (const float*)xin + p*CI + c0;
    float4 a0 = *(const float4*)(xr);
    float4 a1 = *(const float4*)(xr+4);
    float4 a2 = *(const float4*)(xr+8);
    float4 a3 = *(const float4*)(xr+12);
    xf[0]=a0.x; xf[1]=a0.y; xf[2]=a0.z; xf[3]=a0.w;
    xf[4]=a1.x; xf[5]=a1.y; xf[6]=a1.z; xf[7]=a1.w;
    xf[8]=a2.x; xf[9]=a2.y; xf[10]=a2.z; xf[11]=a2.w;
    xf[12]=a3.x; xf[13]=a3.y; xf[14]=a3.z; xf[15]=a3.w;
  }
  float rr[16];
  #pragma unroll
  for (int j = 0; j < 16; j++)
    rr[j] = fmaxf(acc[j] + b3f[c0+j] + xf[j], 0.f);
  if (isbf){
    u16 ov[16];
    #pragma unroll
    for (int j = 0; j < 16; j++) ov[j] = f2bf(rr[j]);
    u16* op = (u16*)out + p*CI + c0;
    #pragma unroll
    for (int q = 0; q < 2; q++){
      uint4 pk;
      pk.x = (u32)ov[q*8+0] | ((u32)ov[q*8+1]<<16);
      pk.y = (u32)ov[q*8+2] | ((u32)ov[q*8+3]<<16);
      pk.z = (u32)ov[q*8+4] | ((u32)ov[q*8+5]<<16);
      pk.w = (u32)ov[q*8+6] | ((u32)ov[q*8+7]<<16);
      *(uint4*)(op + q*8) = pk;
    }
  } else {
    float* op = (float*)out + p*CI + c0;
    #pragma unroll
    for (int q = 0; q < 4; q++){
      float4 pk;
      pk.x = rr[q*4+0]; pk.y = rr[q*4+1];
      pk.z = rr[q*4+2]; pk.w = rr[q*4+3];
      *(float4*)(op + q*4) = pk;
    }
  }
}

extern "C" void kernel_launch(void* const* d_in, const int* in_sizes, int n_in,
                              void* d_out, int out_size, void* d_ws, size_t ws_size,
                              hipStream_t stream){
  (void)in_sizes; (void)n_in; (void)out_size; (void)ws_size;
  const void* x   = d_in[0];
  const void* w1  = d_in[1];
  const void* b1  = d_in[2];
  const void* g1  = d_in[3];
  const void* be1 = d_in[4];
  const void* m1  = d_in[5];
  const void* v1  = d_in[6];
  const void* w2  = d_in[7];
  const void* b2  = d_in[8];
  const void* g2  = d_in[9];
  const void* be2 = d_in[10];
  const void* m2  = d_in[11];
  const void* v2  = d_in[12];
  const void* w3  = d_in[13];
  const void* b3  = d_in[14];

  char* ws = (char*)d_ws;
  u16* h1 = (u16*)ws;                                   // PIX*CM bf16 = 25.7 MB
  u16* h2 = (u16*)(ws + (size_t)PIX*CM*2);              // 25.7 MB
  float* wf1 = (float*)(ws + (size_t)PIX*CM*4);
  float* wf2 = wf1 + 32768;
  float* wf3 = wf2 + 4608;
  float* A1  = wf3 + 32768;
  float* B1  = A1 + 128;
  float* A2  = B1 + 128;
  float* B2  = A2 + 128;
  float* b3f = B2 + 128;

  kprep<<<128, 256, 0, stream>>>(w1,b1,g1,be1,m1,v1,w2,b2,g2,be2,m2,v2,w3,b3,
                                 wf1,wf2,wf3,A1,B1,A2,B2,b3f);
  k1<<<PIX/16, 256, 0, stream>>>(x, g1, wf1, A1, B1, h1);
  k2<<<NB*HW, 256, 0, stream>>>(h1, wf2, A2, B2, h2);
  k3<<<PIX/16, 256, 0, stream>>>(h2, wf3, b3f, x, g1, d_out);
}

// Round 4
// 292.534 us; speedup vs baseline: 4.4544x; 4.4544x over previous
//
#include <hip/hip_runtime.h>
#include <stdint.h>

typedef unsigned short u16;
typedef unsigned int   u32;
typedef __attribute__((ext_vector_type(8))) short bf16x8;
typedef __attribute__((ext_vector_type(4))) float f32x4;

#define EPS 1e-3f
#define NB 32
#define HW 56
#define CI 256
#define CM 128
#define PIX (NB*HW*HW)   // 100352

__device__ __forceinline__ float asf(u32 i){ union{u32 u; float f;} t; t.u=i; return t.f; }
__device__ __forceinline__ u16 f2bf(float f){
  union{float f; u32 u;} t; t.f = f;
  u32 x = t.u;
  return (u16)((x + 0x7fffu + ((x>>16)&1u)) >> 16);   // RNE
}

// ---------------- prep: bf16 transposed weights + BN fold ----------------
// w1 input [k=256][n=128] -> w1t bf16 [n=128][k=256]
// w3 input [k=128][n=256] -> w3t bf16 [n=256][k=128]
__global__ __launch_bounds__(256) void kprep(
    const float* __restrict__ w1, const float* __restrict__ b1, const float* __restrict__ g1,
    const float* __restrict__ be1, const float* __restrict__ m1, const float* __restrict__ v1,
    const float* __restrict__ b2, const float* __restrict__ g2,
    const float* __restrict__ be2, const float* __restrict__ m2, const float* __restrict__ v2,
    const float* __restrict__ w3,
    u16* __restrict__ w1t, u16* __restrict__ w3t,
    float* __restrict__ A1, float* __restrict__ B1,
    float* __restrict__ A2, float* __restrict__ B2){
  int i = blockIdx.x*256 + threadIdx.x;
  if (i < 32768){
    { int n = i >> 8, k = i & 255; w1t[i] = f2bf(w1[k*CM + n]); }
    { int n = i >> 7, k = i & 127; w3t[i] = f2bf(w3[k*CI + n]); }
  }
  if (i < 128){
    float s1 = g1[i] * rsqrtf(v1[i] + EPS);
    A1[i] = s1;
    B1[i] = b1[i]*s1 + be1[i] - m1[i]*s1;
    float s2 = g2[i] * rsqrtf(v2[i] + EPS);
    A2[i] = s2;
    B2[i] = b2[i]*s2 + be2[i] - m2[i]*s2;
  }
}

// ---------------- conv1 1x1 256->128 + BN + ReLU (MFMA bf16) ----------------
// block 256 thr (4 waves). Tile M=64 pixels, N=128 (full), K chunks of 64.
// Wave w: n in [w*32, w*32+32) (2 n-tiles), m in [0,64) (4 m-tiles).
#define K1_LS 72   // LDS row stride (u16): 64 + 8 pad -> 2-way bank aliasing (free)
__global__ __launch_bounds__(256) void k1(const float* __restrict__ x,
    const u16* __restrict__ w1t, const float* __restrict__ A1v,
    const float* __restrict__ B1v, u16* __restrict__ h1){
  __shared__ __align__(16) char smem[64*K1_LS*2 + 128*K1_LS*2];  // 27648 B
  u16* As = (u16*)smem;                    // [64][72]
  u16* Bs = (u16*)(smem + 64*K1_LS*2);     // [128][72]
  const int tid  = threadIdx.x;
  const int lane = tid & 63, wv = tid >> 6;
  const int col  = lane & 15, quad = lane >> 4;
  const long p0 = (long)blockIdx.x * 64;
  f32x4 acc[4][2];
  #pragma unroll
  for (int a = 0; a < 4; a++){
    #pragma unroll
    for (int b = 0; b < 2; b++){ acc[a][b][0]=0.f; acc[a][b][1]=0.f; acc[a][b][2]=0.f; acc[a][b][3]=0.f; }
  }
  for (int kc = 0; kc < 4; kc++){
    // stage A: x fp32 -> bf16, 64 rows x 64 k
    #pragma unroll
    for (int r = 0; r < 4; r++){
      int idx = r*256 + tid;
      int m = idx >> 4, f4 = idx & 15;
      float4 v = *(const float4*)(x + (p0+m)*CI + kc*64 + f4*4);
      u32 lo = (u32)f2bf(v.x) | ((u32)f2bf(v.y) << 16);
      u32 hi = (u32)f2bf(v.z) | ((u32)f2bf(v.w) << 16);
      *(uint2*)(As + m*K1_LS + f4*4) = make_uint2(lo, hi);
    }
    // stage B: w1t bf16, 128 rows x 64 k
    #pragma unroll
    for (int r = 0; r < 4; r++){
      int idx = r*256 + tid;
      int n = idx >> 3, u4 = idx & 7;
      uint4 v = *(const uint4*)(w1t + n*CI + kc*64 + u4*8);
      *(uint4*)(Bs + n*K1_LS + u4*8) = v;
    }
    __syncthreads();
    #pragma unroll
    for (int ks = 0; ks < 2; ks++){
      bf16x8 af[4], bfr[2];
      #pragma unroll
      for (int mt = 0; mt < 4; mt++)
        af[mt] = *(const bf16x8*)(As + (mt*16 + col)*K1_LS + ks*32 + quad*8);
      #pragma unroll
      for (int nt = 0; nt < 2; nt++)
        bfr[nt] = *(const bf16x8*)(Bs + (wv*32 + nt*16 + col)*K1_LS + ks*32 + quad*8);
      #pragma unroll
      for (int mt = 0; mt < 4; mt++){
        #pragma unroll
        for (int nt = 0; nt < 2; nt++)
          acc[mt][nt] = __builtin_amdgcn_mfma_f32_16x16x32_bf16(af[mt], bfr[nt], acc[mt][nt], 0, 0, 0);
      }
    }
    __syncthreads();
  }
  // epilogue: BN + ReLU -> bf16, repack via LDS, vector store
  u16* outw = (u16*)smem;   // [64][136], 17408 B
  #pragma unroll
  for (int nt = 0; nt < 2; nt++){
    int n = wv*32 + nt*16 + col;
    float a1 = A1v[n], b1v = B1v[n];
    #pragma unroll
    for (int mt = 0; mt < 4; mt++){
      #pragma unroll
      for (int reg = 0; reg < 4; reg++){
        int m = mt*16 + quad*4 + reg;
        outw[m*136 + n] = f2bf(fmaxf(acc[mt][nt][reg]*a1 + b1v, 0.f));
      }
    }
  }
  __syncthreads();
  #pragma unroll
  for (int r = 0; r < 4; r++){
    int idx = r*256 + tid;
    int m = idx >> 4, u4 = idx & 15;
    uint4 v = *(const uint4*)(outw + m*136 + u4*8);
    *(uint4*)(h1 + (p0+m)*CM + u4*8) = v;
  }
}

// ---------------- grouped 3x3 conv (32 groups of 4) + BN + ReLU ----------------
#define TW 58
#define CPAD 132
__global__ __launch_bounds__(256) void k2(const u16* __restrict__ h1,
    const float* __restrict__ wf2, const float* __restrict__ A2v,
    const float* __restrict__ B2v, u16* __restrict__ h2){
  __shared__ u16 tile[3][TW][CPAD];
  __shared__ float wsh[9*4*CM];
  const int tid = threadIdx.x;
  const int img = blockIdx.x / HW, y = blockIdx.x % HW;
  for (int i = tid; i < 4608; i += 256) wsh[i] = wf2[i];
  #pragma unroll
  for (int r = 0; r < 3; r++){
    const int yy = y + r - 1;
    if (yy < 0 || yy >= HW){
      u32* t = (u32*)&tile[r][0][0];
      for (int i = tid; i < TW*CPAD/2; i += 256) t[i] = 0u;
    } else {
      if (tid < CPAD){ tile[r][0][tid] = 0; tile[r][TW-1][tid] = 0; }
      const uint4* src = (const uint4*)(h1 + (size_t)(img*HW + yy)*HW*CM);
      for (int i = tid; i < 896; i += 256){
        uint4 v = src[i];
        int px = i >> 4, ch = (i & 15)*8;
        u16* d = &tile[r][px+1][ch];
        *(uint2*)d     = make_uint2(v.x, v.y);
        *(uint2*)(d+4) = make_uint2(v.z, v.w);
      }
    }
  }
  __syncthreads();
  const int lane = tid & 63, wv = tid >> 6;
  if (lane >= HW) return;
  const int px = lane;
  float acc[8][4];
  u16 ov[32];
  for (int gi = 0; gi < 8; gi++){
    const int cb = (wv*8 + gi)*4;
    float a0=0.f, a1=0.f, a2=0.f, a3=0.f;
    #pragma unroll
    for (int ky = 0; ky < 3; ky++){
      #pragma unroll
      for (int kx = 0; kx < 3; kx++){
        const u16* hp = &tile[ky][px+kx][cb];
        uint2 hv = *(const uint2*)hp;
        float i0 = asf(hv.x<<16), i1 = asf(hv.x&0xffff0000u);
        float i2 = asf(hv.y<<16), i3 = asf(hv.y&0xffff0000u);
        const float* wp = &wsh[(size_t)((ky*3+kx)*4)*CM + cb];
        float4 w0 = *(const float4*)(wp);
        float4 w1 = *(const float4*)(wp+CM);
        float4 w2 = *(const float4*)(wp+2*CM);
        float4 w3 = *(const float4*)(wp+3*CM);
        a0 += i0*w0.x + i1*w1.x + i2*w2.x + i3*w3.x;
        a1 += i0*w0.y + i1*w1.y + i2*w2.y + i3*w3.y;
        a2 += i0*w0.z + i1*w1.z + i2*w2.z + i3*w3.z;
        a3 += i0*w0.w + i1*w1.w + i2*w2.w + i3*w3.w;
      }
    }
    acc[gi][0]=a0; acc[gi][1]=a1; acc[gi][2]=a2; acc[gi][3]=a3;
  }
  const long p = (long)(img*HW + y)*HW + px;
  #pragma unroll
  for (int gi = 0; gi < 8; gi++){
    #pragma unroll
    for (int co = 0; co < 4; co++){
      int c = wv*32 + gi*4 + co;
      ov[gi*4+co] = f2bf(fmaxf(acc[gi][co]*A2v[c] + B2v[c], 0.f));
    }
  }
  u16* op = h2 + p*CM + wv*32;
  #pragma unroll
  for (int q = 0; q < 4; q++){
    uint4 pk;
    pk.x = (u32)ov[q*8+0] | ((u32)ov[q*8+1]<<16);
    pk.y = (u32)ov[q*8+2] | ((u32)ov[q*8+3]<<16);
    pk.z = (u32)ov[q*8+4] | ((u32)ov[q*8+5]<<16);
    pk.w = (u32)ov[q*8+6] | ((u32)ov[q*8+7]<<16);
    *(uint4*)(op + q*8) = pk;
  }
}

// ---------------- conv3 1x1 128->256 + bias + residual + ReLU (MFMA bf16) ----------------
// grid (1568, 2): M=64 pixels, N=128 (half of 256), K=128 single shot.
#define K3_LS 136   // LDS row stride (u16): 128 + 8 pad
__global__ __launch_bounds__(256) void k3(const u16* __restrict__ h2,
    const u16* __restrict__ w3t, const float* __restrict__ b3,
    const float* __restrict__ x, float* __restrict__ out){
  __shared__ __align__(16) char smem[64*K3_LS*2 + 128*K3_LS*2];  // 52224 B
  u16* As = (u16*)smem;                    // [64][136]
  u16* Bs = (u16*)(smem + 64*K3_LS*2);     // [128][136]
  const int tid  = threadIdx.x;
  const int lane = tid & 63, wv = tid >> 6;
  const int col  = lane & 15, quad = lane >> 4;
  const long p0 = (long)blockIdx.x * 64;
  const int n0 = blockIdx.y * 128;
  // stage A: h2 bf16 [p0+m][0..128)
  #pragma unroll
  for (int r = 0; r < 4; r++){
    int idx = r*256 + tid;
    int m = idx >> 4, u4 = idx & 15;
    uint4 v = *(const uint4*)(h2 + (p0+m)*CM + u4*8);
    *(uint4*)(As + m*K3_LS + u4*8) = v;
  }
  // stage B: w3t bf16 [n0+n][0..128)
  #pragma unroll
  for (int r = 0; r < 8; r++){
    int idx = r*256 + tid;
    int n = idx >> 4, u4 = idx & 15;
    uint4 v = *(const uint4*)(w3t + (size_t)(n0+n)*CM + u4*8);
    *(uint4*)(Bs + n*K3_LS + u4*8) = v;
  }
  __syncthreads();
  f32x4 acc[4][2];
  #pragma unroll
  for (int a = 0; a < 4; a++){
    #pragma unroll
    for (int b = 0; b < 2; b++){ acc[a][b][0]=0.f; acc[a][b][1]=0.f; acc[a][b][2]=0.f; acc[a][b][3]=0.f; }
  }
  #pragma unroll
  for (int ks = 0; ks < 4; ks++){
    bf16x8 af[4], bfr[2];
    #pragma unroll
    for (int mt = 0; mt < 4; mt++)
      af[mt] = *(const bf16x8*)(As + (mt*16 + col)*K3_LS + ks*32 + quad*8);
    #pragma unroll
    for (int nt = 0; nt < 2; nt++)
      bfr[nt] = *(const bf16x8*)(Bs + (wv*32 + nt*16 + col)*K3_LS + ks*32 + quad*8);
    #pragma unroll
    for (int mt = 0; mt < 4; mt++){
      #pragma unroll
      for (int nt = 0; nt < 2; nt++)
        acc[mt][nt] = __builtin_amdgcn_mfma_f32_16x16x32_bf16(af[mt], bfr[nt], acc[mt][nt], 0, 0, 0);
    }
  }
  __syncthreads();
  // epilogue: pre-act = acc + bias -> LDS fp32; readback adds residual, relu, store
  float* outb = (float*)smem;   // [64][132] fp32 = 33792 B
  #pragma unroll
  for (int nt = 0; nt < 2; nt++){
    int nl = wv*32 + nt*16 + col;
    float bb = b3[n0 + nl];
    #pragma unroll
    for (int mt = 0; mt < 4; mt++){
      #pragma unroll
      for (int reg = 0; reg < 4; reg++){
        int m = mt*16 + quad*4 + reg;
        outb[m*132 + nl] = acc[mt][nt][reg] + bb;
      }
    }
  }
  __syncthreads();
  #pragma unroll
  for (int r = 0; r < 8; r++){
    int idx = r*256 + tid;
    int m = idx >> 5, f4 = idx & 31;
    float4 pre = *(const float4*)(outb + m*132 + f4*4);
    const float* xr = x + (p0+m)*CI + n0 + f4*4;
    float4 xv = *(const float4*)xr;
    float4 o;
    o.x = fmaxf(pre.x + xv.x, 0.f);
    o.y = fmaxf(pre.y + xv.y, 0.f);
    o.z = fmaxf(pre.z + xv.z, 0.f);
    o.w = fmaxf(pre.w + xv.w, 0.f);
    *(float4*)(out + (p0+m)*CI + n0 + f4*4) = o;
  }
}

extern "C" void kernel_launch(void* const* d_in, const int* in_sizes, int n_in,
                              void* d_out, int out_size, void* d_ws, size_t ws_size,
                              hipStream_t stream){
  (void)in_sizes; (void)n_in; (void)out_size; (void)ws_size;
  const float* x   = (const float*)d_in[0];
  const float* w1  = (const float*)d_in[1];
  const float* b1  = (const float*)d_in[2];
  const float* g1  = (const float*)d_in[3];
  const float* be1 = (const float*)d_in[4];
  const float* m1  = (const float*)d_in[5];
  const float* v1  = (const float*)d_in[6];
  const float* w2  = (const float*)d_in[7];
  const float* b2  = (const float*)d_in[8];
  const float* g2  = (const float*)d_in[9];
  const float* be2 = (const float*)d_in[10];
  const float* m2  = (const float*)d_in[11];
  const float* v2  = (const float*)d_in[12];
  const float* w3  = (const float*)d_in[13];
  const float* b3  = (const float*)d_in[14];

  char* ws = (char*)d_ws;
  u16* h1 = (u16*)ws;                                   // 25.69 MB
  u16* h2 = (u16*)(ws + (size_t)PIX*CM*2);              // 25.69 MB
  u16* w1t = (u16*)(ws + (size_t)PIX*CM*4);             // 64 KB
  u16* w3t = w1t + 32768;                               // 64 KB
  float* A1 = (float*)(w3t + 32768);
  float* B1 = A1 + 128;
  float* A2 = B1 + 128;
  float* B2 = A2 + 128;

  kprep<<<128, 256, 0, stream>>>(w1,b1,g1,be1,m1,v1,b2,g2,be2,m2,v2,w3,
                                 w1t,w3t,A1,B1,A2,B2);
  k1<<<PIX/64, 256, 0, stream>>>(x, w1t, A1, B1, h1);
  k2<<<NB*HW, 256, 0, stream>>>(h1, w2, A2, B2, h2);
  k3<<<dim3(PIX/64, 2), 256, 0, stream>>>(h2, w3t, b3, x, (float*)d_out);
}